// Round 5
// baseline (431.229 us; speedup 1.0000x reference)
//
#include <hip/hip_runtime.h>

#define NFEAT 128
#define H 20
#define DH 64
#define SCAN_T 1024
#define BE 64     // edges per k_mlp block (4 waves x 16)
#define NB 192    // private-histogram blocks (atomic-free counting sort)
#define HW 12800  // max histogram words (supports N <= 51200 bins, 4 u8 counters/word)

typedef __attribute__((ext_vector_type(8))) short short8;
typedef __attribute__((ext_vector_type(4))) float f32x4;

__device__ __forceinline__ unsigned short f2bf(float f) {
    union { float f; unsigned u; } v; v.f = f;
    unsigned r = v.u + 0x7fff + ((v.u >> 16) & 1);   // RNE
    return (unsigned short)(r >> 16);
}
__device__ __forceinline__ unsigned pk2(unsigned short a, unsigned short b) {
    return (unsigned)a | ((unsigned)b << 16);
}
// bf16 element j (0..7) of a uint4 viewed as 8 packed bf16 -> f32. j must be compile-time.
__device__ __forceinline__ float bfel(uint4 v, int j) {
    unsigned word = (j < 2) ? v.x : (j < 4) ? v.y : (j < 6) ? v.z : v.w;
    unsigned u = (j & 1) ? (word & 0xFFFF0000u) : (word << 16);
    return __int_as_float((int)u);
}

// DPP 16-lane sum (within each 16-lane row): VALU pipe only. All 16 lanes get the total.
template <int CTRL>
__device__ __forceinline__ float dpp_add(float x) {
    int y = __builtin_amdgcn_update_dpp(0, __float_as_int(x), CTRL, 0xF, 0xF, true);
    return x + __int_as_float(y);
}
__device__ __forceinline__ float sum16(float x) {
    x = dpp_add<0xB1>(x);    // quad_perm [1,0,3,2]
    x = dpp_add<0x4E>(x);    // quad_perm [2,3,0,1]
    x = dpp_add<0x124>(x);   // row_ror:4
    x = dpp_add<0x128>(x);   // row_ror:8
    return x;
}

// ---------------- prep: zero deg/csum/bcat2 + pack decoder B-fragments ----------------
__global__ __launch_bounds__(256) void k_prep(const float* __restrict__ Wd1,
                                              unsigned short* __restrict__ Bd1,
                                              int* __restrict__ deg, int* __restrict__ csum,
                                              float* __restrict__ bcat2, int N) {
    int t = blockIdx.x * blockDim.x + threadIdx.x;
    if (t < N) deg[t] = 0;   // needed by the CSR-atomic fallback path
    if (t < 256) csum[t] = 0;
    if (t < 64) bcat2[t] = 0.f;   // zero-pad so k_mlp's unmasked bias loads are clean
    if (t < 256) {
        int f = t >> 6, l = t & 63;
        int n = f * 16 + (l & 15);
#pragma unroll
        for (int j = 0; j < 8; j++) {
            int k = (l >> 4) * 8 + j;
            float v = (k < H) ? Wd1[k * DH + n] : 0.f;
            Bd1[(size_t)f * 512 + l * 8 + j] = f2bf(v);
        }
    }
}

// ================= atomic-free counting sort (main path) =================
// Per-block histogram of cols into packed u8x4 LDS counters; also accumulates
// per-256-bin chunk sums (LDS-aggregated, ~NB*196 global atomics total — noise).
__global__ __launch_bounds__(512) void k_hist(const int* __restrict__ cols,
                                              unsigned* __restrict__ hist, int* __restrict__ csum,
                                              int E, int N) {
    __shared__ unsigned h[HW];
    __shared__ int cs[256];
    int wstride = (N + 3) >> 2;
    int nchunks = (N + 255) >> 8;
    for (int i = threadIdx.x; i < wstride; i += 512) h[i] = 0;
    if (threadIdx.x < 256) cs[threadIdx.x] = 0;
    __syncthreads();
    int chunk = (E + NB - 1) / NB;
    int beg = blockIdx.x * chunk, end = min(beg + chunk, E);
    for (int i = beg + threadIdx.x; i < end; i += 512) {
        int c = __builtin_nontemporal_load(cols + i);
        atomicAdd(&h[c >> 2], 1u << ((c & 3) * 8));   // per-(block,bin) count < 256
    }
    __syncthreads();
    unsigned* dst = hist + (size_t)blockIdx.x * wstride;
    for (int i = threadIdx.x; i < wstride; i += 512) {
        unsigned w = h[i];
        dst[i] = w;                                    // coalesced dump
        if (w) {
            int s = (w & 0xFF) + ((w >> 8) & 0xFF) + ((w >> 16) & 0xFF) + (w >> 24);
            atomicAdd(&cs[i >> 6], s);                 // word i covers bins 4i..4i+3 -> chunk i>>6
        }
    }
    __syncthreads();
    for (int j = threadIdx.x; j < nchunks; j += 512)
        if (cs[j]) atomicAdd(&csum[j], cs[j]);
}

// Exclusive scan of <=256 chunk sums (single block).
__global__ __launch_bounds__(256) void k_scansmall(const int* __restrict__ chunkSum,
                                                   int* __restrict__ chunkOff, int nb) {
    __shared__ int sc[256];
    int t = threadIdx.x;
    int v0 = (t < nb) ? chunkSum[t] : 0;
    sc[t] = v0;
    __syncthreads();
    for (int off = 1; off < 256; off <<= 1) {
        int v = (t >= off) ? sc[t - off] : 0;
        __syncthreads();
        sc[t] += v;
        __syncthreads();
    }
    if (t < nb) chunkOff[t] = sc[t] - v0;   // exclusive
}

// SINGLE-PASS bases: read hist once, cache per-block counts in packed registers
// (fully unrolled -> compile-time indices, no scratch), emit deg + offsets + delta.
__global__ __launch_bounds__(256) void k_bases(const unsigned* __restrict__ hist,
                                               const int* __restrict__ chunkOff,
                                               unsigned char* __restrict__ delta,
                                               int* __restrict__ offsets, int* __restrict__ deg,
                                               int N, int E) {
    __shared__ int sc[256];
    int c = blockIdx.x * 256 + threadIdx.x;
    int wstride = (N + 3) >> 2;
    int sh = (c & 3) * 8;
    bool valid = c < N;
    int cw = valid ? (c >> 2) : 0;
    unsigned cnt[NB / 4];   // NB u8 counts packed 4-per-word, compile-time indexed
    int d = 0;
#pragma unroll
    for (int b = 0; b < NB; b++) {
        unsigned w = hist[(size_t)b * wstride + cw];
        unsigned byte = (w >> sh) & 0xFF;
        if ((b & 3) == 0) cnt[b >> 2] = byte;
        else cnt[b >> 2] |= byte << ((b & 3) * 8);
        d += (int)byte;
    }
    if (!valid) d = 0;
    sc[threadIdx.x] = d;
    __syncthreads();
    for (int off = 1; off < 256; off <<= 1) {
        int v = (threadIdx.x >= off) ? sc[threadIdx.x - off] : 0;
        __syncthreads();
        sc[threadIdx.x] += v;
        __syncthreads();
    }
    if (valid) {
        int base = chunkOff[blockIdx.x] + sc[threadIdx.x] - d;   // global exclusive prefix
        offsets[c] = base;
        deg[c] = d;
        int run = 0;   // deg[c] < 256 -> fits u8
#pragma unroll
        for (int b = 0; b < NB; b++) {
            delta[(size_t)b * N + c] = (unsigned char)run;       // coalesced across threads
            run += (int)((cnt[b >> 2] >> ((b & 3) * 8)) & 0xFF);
        }
    }
    if (blockIdx.x == 0 && threadIdx.x == 0) offsets[N] = E;
}

// Replay chunk; rank via LDS packed-byte cursor (atomic returns old); exact placement.
__global__ __launch_bounds__(512) void k_place(const int* __restrict__ rows, const int* __restrict__ cols,
                                               const int* __restrict__ offsets,
                                               const unsigned char* __restrict__ delta,
                                               unsigned short* __restrict__ srcs, int E, int N) {
    __shared__ unsigned h[HW];
    int wstride = (N + 3) >> 2;
    for (int i = threadIdx.x; i < wstride; i += 512) h[i] = 0;
    __syncthreads();
    int chunk = (E + NB - 1) / NB;
    int beg = blockIdx.x * chunk, end = min(beg + chunk, E);
    const unsigned char* mydelta = delta + (size_t)blockIdx.x * N;
    for (int i = beg + threadIdx.x; i < end; i += 512) {
        int c = __builtin_nontemporal_load(cols + i);
        int r = __builtin_nontemporal_load(rows + i);
        int sh = (c & 3) * 8;
        unsigned old = atomicAdd(&h[c >> 2], 1u << sh);
        int rank = (old >> sh) & 0xFF;
        int pos = offsets[c] + (int)mydelta[c] + rank;
        srcs[pos] = (unsigned short)r;
    }
}

// ---------------- CSR fallback path (global atomics; used only if ws too small) ----------------
__global__ __launch_bounds__(256) void k_deg(const int* __restrict__ cols, int* __restrict__ deg, int E) {
    int t = blockIdx.x * blockDim.x + threadIdx.x;
    if (t < E) atomicAdd(&deg[cols[t]], 1);
}

__global__ __launch_bounds__(SCAN_T) void k_scan(const int* __restrict__ deg, int* __restrict__ offsets,
                                                 int* __restrict__ cursor, int N) {
    __shared__ int sums[SCAN_T];
    int t = threadIdx.x;
    int chunk = (N + SCAN_T - 1) / SCAN_T;
    int beg = t * chunk;
    int end = min(beg + chunk, N);
    int s = 0;
    for (int i = beg; i < end; i++) s += deg[i];
    sums[t] = s;
    __syncthreads();
    for (int off = 1; off < SCAN_T; off <<= 1) {
        int v = (t >= off) ? sums[t - off] : 0;
        __syncthreads();
        sums[t] += v;
        __syncthreads();
    }
    int run = (t == 0) ? 0 : sums[t - 1];
    for (int i = beg; i < end; i++) {
        offsets[i] = run;
        cursor[i] = run;
        run += deg[i];
    }
    if (t == SCAN_T - 1) offsets[N] = sums[SCAN_T - 1];
}

__global__ __launch_bounds__(256) void k_bucket_csr(const int* __restrict__ rows, const int* __restrict__ cols,
                                                    int* __restrict__ cursor, int* __restrict__ srcs, int E) {
    int e = blockIdx.x * blockDim.x + threadIdx.x;
    if (e >= E) return;
    int pos = atomicAdd(&cursor[cols[e]], 1);
    srcs[pos] = rows[e];
}

// ---------------- xs = (x @ W_gc) * rsqrt(deg+1) ----------------
__global__ __launch_bounds__(256) void k_xw_xs(const float* __restrict__ x, const float* __restrict__ Wgc,
                                               const int* __restrict__ deg,
                                               float* __restrict__ xs, int N) {
    __shared__ float Ws[NFEAT * H];
    for (int i = threadIdx.x; i < NFEAT * H; i += blockDim.x) Ws[i] = Wgc[i];
    __syncthreads();
    int n = blockIdx.x * blockDim.x + threadIdx.x;
    if (n >= N) return;
    float acc[H];
#pragma unroll
    for (int j = 0; j < H; j++) acc[j] = 0.f;
    const float4* x4 = (const float4*)(x + (size_t)n * NFEAT);
#pragma unroll 4
    for (int k4 = 0; k4 < NFEAT / 4; k4++) {
        float4 xv = x4[k4];
#pragma unroll
        for (int s = 0; s < 4; s++) {
            float xk = (s == 0) ? xv.x : (s == 1) ? xv.y : (s == 2) ? xv.z : xv.w;
            const float4* wrow = (const float4*)(Ws + (k4 * 4 + s) * H);
#pragma unroll
            for (int q = 0; q < 5; q++) {
                float4 w = wrow[q];
                acc[q * 4 + 0] += xk * w.x;
                acc[q * 4 + 1] += xk * w.y;
                acc[q * 4 + 2] += xk * w.z;
                acc[q * 4 + 3] += xk * w.w;
            }
        }
    }
    float di = rsqrtf((float)(deg[n] + 1));
    float4* o = (float4*)(xs + (size_t)n * H);
#pragma unroll
    for (int q = 0; q < 5; q++)
        o[q] = make_float4(acc[q * 4 + 0] * di, acc[q * 4 + 1] * di, acc[q * 4 + 2] * di, acc[q * 4 + 3] * di);
}

// ---------------- gather: 16 lanes per node, DPP reduce, emit head-projection tables ----------------
// PA[n] = [x1n@Wmu[0:20] | x1n@Wvar[0:20]]  (r-side), PB[n] = rows 20..40 (c-side).
// Layout per node row (96 B): 3 chunks x { mu[8] bf16 (16B) | var[8] bf16 (16B) },
// chunk q holds dims 8q..8q+7 (dims >= 20 zero) — exactly one MFMA-A k-chunk.
template <typename IT>
__device__ __forceinline__ void gather_core16(const float* __restrict__ xs, const IT* __restrict__ idx,
                                              int beg, int end, int n, int sl, int degn,
                                              const float* __restrict__ bgc,
                                              unsigned short* __restrict__ PAo, unsigned short* __restrict__ PBo,
                                              int nid, const float* __restrict__ Wmu, const float* __restrict__ Wvar,
                                              const float* __restrict__ bmu, const float* __restrict__ bvar,
                                              float* __restrict__ bcat2) {
    float acc[H];
    if (sl == 0) {   // self-loop term counted once
        const float4* self = (const float4*)(xs + (size_t)n * H);
#pragma unroll
        for (int q = 0; q < 5; q++) {
            float4 v = self[q];
            acc[q * 4 + 0] = v.x; acc[q * 4 + 1] = v.y; acc[q * 4 + 2] = v.z; acc[q * 4 + 3] = v.w;
        }
    } else {
#pragma unroll
        for (int j = 0; j < H; j++) acc[j] = 0.f;
    }
#pragma unroll 2
    for (int i = beg + sl; i < end; i += 16) {
        int r = (int)__builtin_nontemporal_load(idx + i);   // touch-once: keep xs L2-resident
        const float4* p = (const float4*)(xs + (size_t)r * H);
#pragma unroll
        for (int q = 0; q < 5; q++) {
            float4 v = p[q];
            acc[q * 4 + 0] += v.x; acc[q * 4 + 1] += v.y; acc[q * 4 + 2] += v.z; acc[q * 4 + 3] += v.w;
        }
    }
#pragma unroll
    for (int j = 0; j < H; j++) acc[j] = sum16(acc[j]);    // all 16 lanes hold the totals
    float di = rsqrtf((float)(degn + 1));
    float x1f[H];
#pragma unroll
    for (int j = 0; j < H; j++) x1f[j] = fmaxf(di * acc[j] + bgc[j], 0.f);

    // ---- head projections: 96 bf16 values/node (4 parts x 24 dims), 6 per lane ----
#pragma unroll
    for (int t = 0; t < 6; t++) {
        int v = sl + 16 * t;          // 0..95
        int part = v / 24;            // 0:PAmu 1:PAvar 2:PBmu 3:PBvar
        int j = v - part * 24;        // 0..23 (>=20 -> zero pad)
        float s = 0.f;
        if (j < 20) {
            const float* W = (part & 1) ? Wvar : Wmu;
            int k0 = (part < 2) ? 0 : 20;
#pragma unroll
            for (int k = 0; k < H; k++) s += x1f[k] * W[(k0 + k) * H + j];
        }
        unsigned short* T = (part < 2) ? PAo : PBo;
        int off = (j >> 3) * 16 + (part & 1) * 8 + (j & 7);   // u16 units within 48-u16 row
        T[(size_t)n * 48 + off] = f2bf(s);
    }

    if (n == nid) {   // nid head-bias fold: 16 lanes split the 40 bias dots
#pragma unroll
        for (int base = 0; base < 48; base += 16) {
            int jj = base + sl;
            if (jj < 40) {
                bool ismu = jj < 20;
                int col = ismu ? jj : jj - 20;
                const float* W = ismu ? Wmu : Wvar;
                float s = ismu ? bmu[col] : bvar[col];
#pragma unroll
                for (int k = 0; k < H; k++) s += x1f[k] * W[(2 * H + k) * H + col];
                bcat2[jj] = s;
            }
        }
    }
}

__global__ __launch_bounds__(256) void k_gather_csr16(const float* __restrict__ xs, const unsigned short* __restrict__ srcs,
                                                      const int* __restrict__ offsets, const int* __restrict__ deg,
                                                      const float* __restrict__ bgc,
                                                      unsigned short* __restrict__ PAo, unsigned short* __restrict__ PBo,
                                                      const int* __restrict__ node_id,
                                                      const float* __restrict__ Wmu, const float* __restrict__ Wvar,
                                                      const float* __restrict__ bmu, const float* __restrict__ bvar,
                                                      float* __restrict__ bcat2, int N) {
    int wave = (blockIdx.x * 256 + threadIdx.x) >> 6;
    int lane = threadIdx.x & 63;
    int n = wave * 4 + (lane >> 4);
    if (n >= N) return;
    gather_core16(xs, srcs, offsets[n], offsets[n + 1], n, lane & 15, deg[n], bgc, PAo, PBo,
                  node_id[0], Wmu, Wvar, bmu, bvar, bcat2);
}

__global__ __launch_bounds__(256) void k_gather_csr(const float* __restrict__ xs, const int* __restrict__ srcs,
                                                    const int* __restrict__ offsets, const int* __restrict__ deg,
                                                    const float* __restrict__ bgc,
                                                    unsigned short* __restrict__ PAo, unsigned short* __restrict__ PBo,
                                                    const int* __restrict__ node_id,
                                                    const float* __restrict__ Wmu, const float* __restrict__ Wvar,
                                                    const float* __restrict__ bmu, const float* __restrict__ bvar,
                                                    float* __restrict__ bcat2, int N) {
    int wave = (blockIdx.x * 256 + threadIdx.x) >> 6;
    int lane = threadIdx.x & 63;
    int n = wave * 4 + (lane >> 4);
    if (n >= N) return;
    gather_core16(xs, srcs, offsets[n], offsets[n + 1], n, lane & 15, deg[n], bgc, PAo, PBo,
                  node_id[0], Wmu, Wvar, bmu, bvar, bcat2);
}

// ---------------- fused per-edge MLP: LDS-free, barrier-free ----------------
// Heads are per-node precomputed (PA/PB); each lane builds its decoder A-fragment
// directly in registers: z[k] = PAmu[r][k]+PBmu[c][k]+bm[k] + exp(PAvar+PBvar+bv)*noise.
// Per lane: ~5 vector loads + ~150 VALU + 4 MFMAs. No __syncthreads anywhere.
__global__ __launch_bounds__(256) void k_mlp(
    const unsigned short* __restrict__ PA, const unsigned short* __restrict__ PBt,
    const int* __restrict__ rows, const int* __restrict__ cols,
    const float* __restrict__ noise_n, const float* __restrict__ noise_u,
    const unsigned short* __restrict__ Bd1g,
    const float* __restrict__ bcat2, const float* __restrict__ b_d1,
    const float* __restrict__ W_d2, const float* __restrict__ b_d2,
    float* __restrict__ out, int E) {

    int tid = threadIdx.x;
    int e0 = blockIdx.x * BE;
    int l = tid & 63, w = tid >> 6;
    int m = l & 15, quad = l >> 4;

    int ea = e0 + w * 16 + m;               // this lane's A-row edge
    int ec = (ea < E) ? ea : E - 1;
    int r = rows[ec], c = cols[ec];

    // ---- gather z ingredients for k-dims quad*8 .. quad*8+7 ----
    uint4 pam = {0, 0, 0, 0}, pav = {0, 0, 0, 0}, pbm = {0, 0, 0, 0}, pbv = {0, 0, 0, 0};
    float nz[8], bm[8], bv[8];
#pragma unroll
    for (int j = 0; j < 8; j++) { nz[j] = 0.f; bm[j] = 0.f; bv[j] = 0.f; }
    if (quad < 3) {
        const char* pa = (const char*)PA + (size_t)r * 96 + quad * 32;
        const char* pb = (const char*)PBt + (size_t)c * 96 + quad * 32;
        pam = *(const uint4*)pa;  pav = *(const uint4*)(pa + 16);
        pbm = *(const uint4*)pb;  pbv = *(const uint4*)(pb + 16);
        float4 b0 = *(const float4*)(bcat2 + quad * 8);        // bcat2 zero-padded to 64
        float4 b1 = *(const float4*)(bcat2 + quad * 8 + 4);
        bm[0] = b0.x; bm[1] = b0.y; bm[2] = b0.z; bm[3] = b0.w;
        bm[4] = b1.x; bm[5] = b1.y; bm[6] = b1.z; bm[7] = b1.w;
        float4 v0 = *(const float4*)(bcat2 + 20 + quad * 8);
        float4 v1 = *(const float4*)(bcat2 + 20 + quad * 8 + 4);
        bv[0] = v0.x; bv[1] = v0.y; bv[2] = v0.z; bv[3] = v0.w;
        bv[4] = v1.x; bv[5] = v1.y; bv[6] = v1.z; bv[7] = v1.w;
        const float* np = noise_n + (size_t)ec * H + quad * 8;
        float4 n0 = *(const float4*)np;
        nz[0] = n0.x; nz[1] = n0.y; nz[2] = n0.z; nz[3] = n0.w;
        if (quad < 2) {   // quad 2 second half is dims 20..23 (pad) -> avoid OOB at e=E-1
            float4 n1 = *(const float4*)(np + 4);
            nz[4] = n1.x; nz[5] = n1.y; nz[6] = n1.z; nz[7] = n1.w;
        }
    }

    // ---- z = mu + exp(lv)*noise, packed straight into the MFMA A-fragment ----
    unsigned zp[4];
#pragma unroll
    for (int jj = 0; jj < 4; jj++) {
        unsigned short zh[2];
#pragma unroll
        for (int h2 = 0; h2 < 2; h2++) {
            int j = jj * 2 + h2;
            float zmu = bfel(pam, j) + bfel(pbm, j) + bm[j];
            float zva = bfel(pav, j) + bfel(pbv, j) + bv[j];
            float z = zmu + __expf(zva) * nz[j];
            z = (quad * 8 + j < 20) ? z : 0.f;   // zero the k-padding (also kills bias garbage)
            zh[h2] = f2bf(z);
        }
        zp[jj] = pk2(zh[0], zh[1]);
    }
    union { unsigned u[4]; short8 s; } au;
    au.u[0] = zp[0]; au.u[1] = zp[1]; au.u[2] = zp[2]; au.u[3] = zp[3];
    short8 a2 = au.s;

    // ---- decoder: h = relu(z @ Wd1 + b), sw = relu(h . wd2 + b2), log-free gumbel gate ----
    float p0 = 0.f, p1 = 0.f, p2 = 0.f, p3 = 0.f;
#pragma unroll
    for (int t4 = 0; t4 < 4; t4++) {
        f32x4 acc = {0.f, 0.f, 0.f, 0.f};
        short8 bb = *(const short8*)(Bd1g + t4 * 512 + l * 8);
        acc = __builtin_amdgcn_mfma_f32_16x16x32_bf16(a2, bb, acc, 0, 0, 0);
        int col = t4 * 16 + m;
        float bias = b_d1[col], wo = W_d2[col];
        p0 += fmaxf(acc[0] + bias, 0.f) * wo;
        p1 += fmaxf(acc[1] + bias, 0.f) * wo;
        p2 += fmaxf(acc[2] + bias, 0.f) * wo;
        p3 += fmaxf(acc[3] + bias, 0.f) * wo;
    }
    p0 = sum16(p0); p1 = sum16(p1); p2 = sum16(p2); p3 = sum16(p3);
    if (m < 4) {
        float swv = (m == 0) ? p0 : (m == 1) ? p1 : (m == 2) ? p2 : p3;
        int e = e0 + w * 16 + quad * 4 + m;
        if (e < E) {
            float sw = fmaxf(swv + b_d2[0], 0.f);
            float u = noise_u[e];
            float ev = 0.9999f - 0.9998f * u;
            // sigmoid(log(ev/(1-ev)) + sw) == ev / (ev + (1-ev)*exp(-sw))
            float t = __expf(-sw);
            out[e] = ev / (ev + (1.f - ev) * t);
        }
    }
}

extern "C" void kernel_launch(void* const* d_in, const int* in_sizes, int n_in,
                              void* d_out, int out_size, void* d_ws, size_t ws_size,
                              hipStream_t stream) {
    const int N = in_sizes[0] / NFEAT;   // 50000
    const int E = in_sizes[1] / 2;       // 1600000

    const float* x       = (const float*)d_in[0];
    const int*   ei      = (const int*)d_in[1];
    const int*   rows    = ei;
    const int*   cols    = ei + E;
    const int*   node_id = (const int*)d_in[2];
    const float* noise_n = (const float*)d_in[3];
    const float* noise_u = (const float*)d_in[4];
    const float* Wgc  = (const float*)d_in[5];
    const float* bgc  = (const float*)d_in[6];
    const float* Wmu  = (const float*)d_in[7];
    const float* bmu  = (const float*)d_in[8];
    const float* Wvar = (const float*)d_in[9];
    const float* bvar = (const float*)d_in[10];
    const float* Wd1  = (const float*)d_in[11];
    const float* bd1  = (const float*)d_in[12];
    const float* Wd2  = (const float*)d_in[13];
    const float* bd2  = (const float*)d_in[14];
    float* out = (float*)d_out;

    const int B = 256;
    int gN  = (N + B - 1) / B;
    int gG  = (N + 15) / 16;            // gather: 16 nodes per block (4 waves x 4 nodes)
    int gE  = (E + B - 1) / B;
    int gM  = (E + BE - 1) / BE;
    int nBins = (N + 255) / 256;        // <= 256 for N <= 65536

    char* ws = (char*)d_ws;
    size_t wstride   = (size_t)((N + 3) >> 2);
    size_t pa_sz     = (((size_t)N * 96) + 255) & ~255ULL;
    size_t hist_sz   = ((NB * wstride * 4) + 255) & ~255ULL;
    size_t histreg   = (hist_sz > 2 * pa_sz) ? hist_sz : 2 * pa_sz;   // PA/PB alias dead hist
    // main-path layout (256B-aligned regions)
    size_t o_deg     = 0;
    size_t o_off     = o_deg  + (((size_t)N * 4 + 255) & ~255ULL);
    size_t o_csum    = o_off  + (((size_t)(N + 1) * 4 + 255) & ~255ULL);
    size_t o_coff    = o_csum + 1024;
    size_t o_hist    = o_coff + 1024;
    size_t o_delta   = o_hist  + histreg;
    size_t o_srcs    = o_delta + (((size_t)NB * N + 255) & ~255ULL);
    size_t o_xs      = o_srcs  + (((size_t)E * 2 + 255) & ~255ULL);
    size_t o_Bd1     = o_xs    + (((size_t)N * H * 4 + 255) & ~255ULL);
    size_t o_bcat2   = o_Bd1   + 4096;
    size_t need      = o_bcat2 + 256;

    bool main_path = (ws_size >= need) && (N <= 4 * HW) && (N < 65536) && (nBins <= 256);

    if (main_path) {
        int*   deg     = (int*)(ws + o_deg);
        int*   offsets = (int*)(ws + o_off);
        int*   csum    = (int*)(ws + o_csum);
        int*   coff    = (int*)(ws + o_coff);
        unsigned* hist = (unsigned*)(ws + o_hist);
        unsigned short* PA = (unsigned short*)(ws + o_hist);            // alias (dead after k_place)
        unsigned short* PB = (unsigned short*)(ws + o_hist + pa_sz);
        unsigned char* delta = (unsigned char*)(ws + o_delta);
        unsigned short* srcs = (unsigned short*)(ws + o_srcs);
        float* xs      = (float*)(ws + o_xs);
        unsigned short* Bd1  = (unsigned short*)(ws + o_Bd1);
        float* bcat2   = (float*)(ws + o_bcat2);

        k_prep<<<gN, B, 0, stream>>>(Wd1, Bd1, deg, csum, bcat2, N);
        k_hist<<<NB, 512, 0, stream>>>(cols, hist, csum, E, N);
        k_scansmall<<<1, B, 0, stream>>>(csum, coff, nBins);
        k_bases<<<nBins, B, 0, stream>>>(hist, coff, delta, offsets, deg, N, E);
        k_xw_xs<<<gN, B, 0, stream>>>(x, Wgc, deg, xs, N);
        k_place<<<NB, 512, 0, stream>>>(rows, cols, offsets, delta, srcs, E, N);
        k_gather_csr16<<<gG, B, 0, stream>>>(xs, srcs, offsets, deg, bgc, PA, PB,
                                             node_id, Wmu, Wvar, bmu, bvar, bcat2, N);
        k_mlp<<<gM, B, 0, stream>>>(PA, PB, rows, cols, noise_n, noise_u,
                                    Bd1, bcat2, bd1, Wd2, bd2, out, E);
    } else {
        size_t f_deg   = 0;
        size_t f_off   = f_deg + (((size_t)N * 4 + 255) & ~255ULL);
        size_t f_cur   = f_off + (((size_t)(N + 1) * 4 + 255) & ~255ULL);
        size_t f_srcs  = f_cur + (((size_t)N * 4 + 255) & ~255ULL);
        size_t f_xs    = f_srcs + (((size_t)E * 4 + 255) & ~255ULL);
        size_t f_PA    = f_xs + (((size_t)N * H * 4 + 255) & ~255ULL);
        size_t f_PB    = f_PA + pa_sz;
        size_t f_Bd1   = f_PB + pa_sz;
        size_t f_bcat2 = f_Bd1 + 4096;

        int*   deg     = (int*)(ws + f_deg);
        int*   offsets = (int*)(ws + f_off);
        int*   cursor  = (int*)(ws + f_cur);
        int*   srcs    = (int*)(ws + f_srcs);
        float* xs      = (float*)(ws + f_xs);
        unsigned short* PA = (unsigned short*)(ws + f_PA);
        unsigned short* PB = (unsigned short*)(ws + f_PB);
        unsigned short* Bd1 = (unsigned short*)(ws + f_Bd1);
        float* bcat2   = (float*)(ws + f_bcat2);

        k_prep<<<gN, B, 0, stream>>>(Wd1, Bd1, deg, cursor, bcat2, N);
        k_deg<<<gE, B, 0, stream>>>(cols, deg, E);
        k_scan<<<1, SCAN_T, 0, stream>>>(deg, offsets, cursor, N);
        k_bucket_csr<<<gE, B, 0, stream>>>(rows, cols, cursor, srcs, E);
        k_xw_xs<<<gN, B, 0, stream>>>(x, Wgc, deg, xs, N);
        k_gather_csr<<<gG, B, 0, stream>>>(xs, srcs, offsets, deg, bgc, PA, PB,
                                           node_id, Wmu, Wvar, bmu, bvar, bcat2, N);
        k_mlp<<<gM, B, 0, stream>>>(PA, PB, rows, cols, noise_n, noise_u,
                                    Bd1, bcat2, bd1, Wd2, bd2, out, E);
    }
}

// Round 6
// 428.377 us; speedup vs baseline: 1.0067x; 1.0067x over previous
//
#include <hip/hip_runtime.h>

#define NFEAT 128
#define H 20
#define DH 64
#define SCAN_T 1024
#define BE 64     // edges per k_mlp block (4 waves x 16)
#define NB 192    // private-histogram blocks (atomic-free counting sort)
#define HW 12800  // max histogram words (supports N <= 51200 bins, 4 u8 counters/word)

typedef __attribute__((ext_vector_type(8))) short short8;
typedef __attribute__((ext_vector_type(4))) float f32x4;

__device__ __forceinline__ unsigned short f2bf(float f) {
    union { float f; unsigned u; } v; v.f = f;
    unsigned r = v.u + 0x7fff + ((v.u >> 16) & 1);   // RNE
    return (unsigned short)(r >> 16);
}
__device__ __forceinline__ unsigned pk2(unsigned short a, unsigned short b) {
    return (unsigned)a | ((unsigned)b << 16);
}

// DPP 16-lane sum (within each 16-lane row): VALU pipe only. All 16 lanes get the total.
template <int CTRL>
__device__ __forceinline__ float dpp_add(float x) {
    int y = __builtin_amdgcn_update_dpp(0, __float_as_int(x), CTRL, 0xF, 0xF, true);
    return x + __int_as_float(y);
}
__device__ __forceinline__ float sum16(float x) {
    x = dpp_add<0xB1>(x);    // quad_perm [1,0,3,2]
    x = dpp_add<0x4E>(x);    // quad_perm [2,3,0,1]
    x = dpp_add<0x124>(x);   // row_ror:4
    x = dpp_add<0x128>(x);   // row_ror:8
    return x;
}

// ---------------- prep: zero deg/csum/bcat2 + pack head A-frags (W^T) + decoder B-frags ----------------
// Head MFMA is operand-swapped: D[dim][edge] = A(=W^T) x B(=x2). A-frag f = h*4 + t*2 + s:
// h in {mu,var}, t = dim-tile (0: d0-15, 1: d16-31), s = k-step (0: k0-31, 1: k32-63).
// A[d][k] = W[k][d] for k<40 (rows 0:20 = src-part, 20:40 = dst-part), d<20; else 0.
// nid rows (40:60) are folded into bcat2 by the gather kernel.
__global__ __launch_bounds__(256) void k_prep(const float* __restrict__ Wmu, const float* __restrict__ Wvar,
                                              const float* __restrict__ Wd1,
                                              unsigned short* __restrict__ Bh2, unsigned short* __restrict__ Bd1,
                                              int* __restrict__ deg, int* __restrict__ csum,
                                              float* __restrict__ bcat2, int N) {
    int t = blockIdx.x * blockDim.x + threadIdx.x;
    if (t < N) deg[t] = 0;   // needed by the CSR-atomic fallback path
    if (t < 256) csum[t] = 0;
    if (t < 128) bcat2[t] = 0.f;   // [0:20 mu | 64:84 var], zero-padded
    if (t < 512) {
        int f = t >> 6, l = t & 63;
        int h = f >> 2, tt = (f >> 1) & 1, s = f & 1;
        const float* W = h ? Wvar : Wmu;
        int d = tt * 16 + (l & 15);
#pragma unroll
        for (int j = 0; j < 8; j++) {
            int k = s * 32 + (l >> 4) * 8 + j;
            float v = (k < 2 * H && d < H) ? W[k * H + d] : 0.f;
            Bh2[(size_t)f * 512 + l * 8 + j] = f2bf(v);
        }
    } else if (t < 768) {
        int f = (t - 512) >> 6, l = t & 63;
        int n = f * 16 + (l & 15);
#pragma unroll
        for (int j = 0; j < 8; j++) {
            int k = (l >> 4) * 8 + j;
            float v = (k < H) ? Wd1[k * DH + n] : 0.f;
            Bd1[(size_t)f * 512 + l * 8 + j] = f2bf(v);
        }
    }
}

// ================= atomic-free counting sort (main path) =================
// Per-block histogram of cols into packed u8x4 LDS counters; the atomic's return value
// IS the edge's within-(block,bin) rank -> stored (u8) so k_place needs no LDS replay.
__global__ __launch_bounds__(512) void k_hist(const int* __restrict__ cols,
                                              unsigned* __restrict__ hist, int* __restrict__ csum,
                                              unsigned char* __restrict__ rank,
                                              int E, int N) {
    __shared__ unsigned h[HW];
    __shared__ int cs[256];
    int wstride = (N + 3) >> 2;
    int nchunks = (N + 255) >> 8;
    for (int i = threadIdx.x; i < wstride; i += 512) h[i] = 0;
    if (threadIdx.x < 256) cs[threadIdx.x] = 0;
    __syncthreads();
    int chunk = (E + NB - 1) / NB;
    int beg = blockIdx.x * chunk, end = min(beg + chunk, E);
    for (int i = beg + threadIdx.x; i < end; i += 512) {
        int c = __builtin_nontemporal_load(cols + i);
        int sh = (c & 3) * 8;
        unsigned old = atomicAdd(&h[c >> 2], 1u << sh);   // per-(block,bin) count < 256
        rank[i] = (unsigned char)((old >> sh) & 0xFF);
    }
    __syncthreads();
    unsigned* dst = hist + (size_t)blockIdx.x * wstride;
    for (int i = threadIdx.x; i < wstride; i += 512) {
        unsigned w = h[i];
        dst[i] = w;                                    // coalesced dump
        if (w) {
            int s = (w & 0xFF) + ((w >> 8) & 0xFF) + ((w >> 16) & 0xFF) + (w >> 24);
            atomicAdd(&cs[i >> 6], s);                 // word i covers bins 4i..4i+3 -> chunk i>>6
        }
    }
    __syncthreads();
    for (int j = threadIdx.x; j < nchunks; j += 512)
        if (cs[j]) atomicAdd(&csum[j], cs[j]);
}

// Exclusive scan of <=256 chunk sums (single block).
__global__ __launch_bounds__(256) void k_scansmall(const int* __restrict__ chunkSum,
                                                   int* __restrict__ chunkOff, int nb) {
    __shared__ int sc[256];
    int t = threadIdx.x;
    int v0 = (t < nb) ? chunkSum[t] : 0;
    sc[t] = v0;
    __syncthreads();
    for (int off = 1; off < 256; off <<= 1) {
        int v = (t >= off) ? sc[t - off] : 0;
        __syncthreads();
        sc[t] += v;
        __syncthreads();
    }
    if (t < nb) chunkOff[t] = sc[t] - v0;   // exclusive
}

// SINGLE-PASS bases: read hist once, cache per-block counts in packed registers
// (fully unrolled -> compile-time indices, no scratch), emit deg + offsets + delta.
__global__ __launch_bounds__(256) void k_bases(const unsigned* __restrict__ hist,
                                               const int* __restrict__ chunkOff,
                                               unsigned char* __restrict__ delta,
                                               int* __restrict__ offsets, int* __restrict__ deg,
                                               int N, int E) {
    __shared__ int sc[256];
    int c = blockIdx.x * 256 + threadIdx.x;
    int wstride = (N + 3) >> 2;
    int sh = (c & 3) * 8;
    bool valid = c < N;
    int cw = valid ? (c >> 2) : 0;
    unsigned cnt[NB / 4];   // NB u8 counts packed 4-per-word, compile-time indexed
    int d = 0;
#pragma unroll
    for (int b = 0; b < NB; b++) {
        unsigned w = hist[(size_t)b * wstride + cw];
        unsigned byte = (w >> sh) & 0xFF;
        if ((b & 3) == 0) cnt[b >> 2] = byte;
        else cnt[b >> 2] |= byte << ((b & 3) * 8);
        d += (int)byte;
    }
    if (!valid) d = 0;
    sc[threadIdx.x] = d;
    __syncthreads();
    for (int off = 1; off < 256; off <<= 1) {
        int v = (threadIdx.x >= off) ? sc[threadIdx.x - off] : 0;
        __syncthreads();
        sc[threadIdx.x] += v;
        __syncthreads();
    }
    if (valid) {
        int base = chunkOff[blockIdx.x] + sc[threadIdx.x] - d;   // global exclusive prefix
        offsets[c] = base;
        deg[c] = d;
        int run = 0;   // deg[c] < 256 -> fits u8
#pragma unroll
        for (int b = 0; b < NB; b++) {
            delta[(size_t)b * N + c] = (unsigned char)run;       // coalesced across threads
            run += (int)((cnt[b >> 2] >> ((b & 3) * 8)) & 0xFF);
        }
    }
    if (blockIdx.x == 0 && threadIdx.x == 0) offsets[N] = E;
}

// Pure scatter placement: no LDS, no atomics, full occupancy.
// pos = offsets[c] + delta[block(e)][c] + rank[e]  (bijective onto [0,E)).
__global__ __launch_bounds__(256) void k_place(const int* __restrict__ rows, const int* __restrict__ cols,
                                               const int* __restrict__ offsets,
                                               const unsigned char* __restrict__ delta,
                                               const unsigned char* __restrict__ rank,
                                               unsigned short* __restrict__ srcs, int E, int N, int chunk) {
    int e = blockIdx.x * 256 + threadIdx.x;
    if (e >= E) return;
    int c = cols[e];
    int r = rows[e];
    int b = e / chunk;   // matches k_hist's block partition
    int pos = offsets[c] + (int)delta[(size_t)b * N + c] + (int)rank[e];
    srcs[pos] = (unsigned short)r;
}

// ---------------- CSR fallback path (global atomics; used only if ws too small) ----------------
__global__ __launch_bounds__(256) void k_deg(const int* __restrict__ cols, int* __restrict__ deg, int E) {
    int t = blockIdx.x * blockDim.x + threadIdx.x;
    if (t < E) atomicAdd(&deg[cols[t]], 1);
}

__global__ __launch_bounds__(SCAN_T) void k_scan(const int* __restrict__ deg, int* __restrict__ offsets,
                                                 int* __restrict__ cursor, int N) {
    __shared__ int sums[SCAN_T];
    int t = threadIdx.x;
    int chunk = (N + SCAN_T - 1) / SCAN_T;
    int beg = t * chunk;
    int end = min(beg + chunk, N);
    int s = 0;
    for (int i = beg; i < end; i++) s += deg[i];
    sums[t] = s;
    __syncthreads();
    for (int off = 1; off < SCAN_T; off <<= 1) {
        int v = (t >= off) ? sums[t - off] : 0;
        __syncthreads();
        sums[t] += v;
        __syncthreads();
    }
    int run = (t == 0) ? 0 : sums[t - 1];
    for (int i = beg; i < end; i++) {
        offsets[i] = run;
        cursor[i] = run;
        run += deg[i];
    }
    if (t == SCAN_T - 1) offsets[N] = sums[SCAN_T - 1];
}

__global__ __launch_bounds__(256) void k_bucket_csr(const int* __restrict__ rows, const int* __restrict__ cols,
                                                    int* __restrict__ cursor, int* __restrict__ srcs, int E) {
    int e = blockIdx.x * blockDim.x + threadIdx.x;
    if (e >= E) return;
    int pos = atomicAdd(&cursor[cols[e]], 1);
    srcs[pos] = rows[e];
}

// ---------------- xs = (x @ W_gc) * rsqrt(deg+1) ----------------
__global__ __launch_bounds__(256) void k_xw_xs(const float* __restrict__ x, const float* __restrict__ Wgc,
                                               const int* __restrict__ deg,
                                               float* __restrict__ xs, int N) {
    __shared__ float Ws[NFEAT * H];
    for (int i = threadIdx.x; i < NFEAT * H; i += blockDim.x) Ws[i] = Wgc[i];
    __syncthreads();
    int n = blockIdx.x * blockDim.x + threadIdx.x;
    if (n >= N) return;
    float acc[H];
#pragma unroll
    for (int j = 0; j < H; j++) acc[j] = 0.f;
    const float4* x4 = (const float4*)(x + (size_t)n * NFEAT);
#pragma unroll 4
    for (int k4 = 0; k4 < NFEAT / 4; k4++) {
        float4 xv = x4[k4];
#pragma unroll
        for (int s = 0; s < 4; s++) {
            float xk = (s == 0) ? xv.x : (s == 1) ? xv.y : (s == 2) ? xv.z : xv.w;
            const float4* wrow = (const float4*)(Ws + (k4 * 4 + s) * H);
#pragma unroll
            for (int q = 0; q < 5; q++) {
                float4 w = wrow[q];
                acc[q * 4 + 0] += xk * w.x;
                acc[q * 4 + 1] += xk * w.y;
                acc[q * 4 + 2] += xk * w.z;
                acc[q * 4 + 3] += xk * w.w;
            }
        }
    }
    float di = rsqrtf((float)(deg[n] + 1));
    float4* o = (float4*)(xs + (size_t)n * H);
#pragma unroll
    for (int q = 0; q < 5; q++)
        o[q] = make_float4(acc[q * 4 + 0] * di, acc[q * 4 + 1] * di, acc[q * 4 + 2] * di, acc[q * 4 + 3] * di);
}

// ---------------- gather (neighbor-parallel): 16 lanes per node, DPP reduce ----------------
// Emits x1 in bf16 (40 B/node table -> L2-resident for k_mlp's gathers).
// Also folds the node_id head contribution into bcat2: mu j -> [j], var j -> [64+j].
template <typename IT>
__device__ __forceinline__ void gather_core16(const float* __restrict__ xs, const IT* __restrict__ idx,
                                              int beg, int end, int n, int sl, int degn,
                                              const float* __restrict__ bgc, unsigned short* __restrict__ x1b,
                                              int nid, const float* __restrict__ Wmu, const float* __restrict__ Wvar,
                                              const float* __restrict__ bmu, const float* __restrict__ bvar,
                                              float* __restrict__ bcat2) {
    float acc[H];
    if (sl == 0) {   // self-loop term counted once
        const float4* self = (const float4*)(xs + (size_t)n * H);
#pragma unroll
        for (int q = 0; q < 5; q++) {
            float4 v = self[q];
            acc[q * 4 + 0] = v.x; acc[q * 4 + 1] = v.y; acc[q * 4 + 2] = v.z; acc[q * 4 + 3] = v.w;
        }
    } else {
#pragma unroll
        for (int j = 0; j < H; j++) acc[j] = 0.f;
    }
#pragma unroll 2
    for (int i = beg + sl; i < end; i += 16) {
        int r = (int)__builtin_nontemporal_load(idx + i);   // touch-once: keep xs L2-resident
        const float4* p = (const float4*)(xs + (size_t)r * H);
#pragma unroll
        for (int q = 0; q < 5; q++) {
            float4 v = p[q];
            acc[q * 4 + 0] += v.x; acc[q * 4 + 1] += v.y; acc[q * 4 + 2] += v.z; acc[q * 4 + 3] += v.w;
        }
    }
#pragma unroll
    for (int j = 0; j < H; j++) acc[j] = sum16(acc[j]);    // all 16 lanes hold the totals
    float di = rsqrtf((float)(degn + 1));
    float x1f[H];
#pragma unroll
    for (int j = 0; j < H; j++) x1f[j] = fmaxf(di * acc[j] + bgc[j], 0.f);
    if (sl == 0) {
        unsigned o[10];
#pragma unroll
        for (int j = 0; j < 10; j++) o[j] = pk2(f2bf(x1f[2 * j]), f2bf(x1f[2 * j + 1]));
        unsigned* dst = (unsigned*)(x1b + (size_t)n * H);
        *(uint4*)dst = make_uint4(o[0], o[1], o[2], o[3]);
        *(uint4*)(dst + 4) = make_uint4(o[4], o[5], o[6], o[7]);
        *(uint2*)(dst + 8) = make_uint2(o[8], o[9]);
    }
    if (n == nid) {   // nid head-bias fold: 16 lanes split the 40 bias dots
#pragma unroll
        for (int base = 0; base < 48; base += 16) {
            int jj = base + sl;
            if (jj < 40) {
                bool ismu = jj < 20;
                int col = ismu ? jj : jj - 20;
                const float* W = ismu ? Wmu : Wvar;
                float s = ismu ? bmu[col] : bvar[col];
#pragma unroll
                for (int k = 0; k < H; k++) s += x1f[k] * W[(2 * H + k) * H + col];
                bcat2[ismu ? col : 64 + col] = s;
            }
        }
    }
}

__global__ __launch_bounds__(256) void k_gather_csr16(const float* __restrict__ xs, const unsigned short* __restrict__ srcs,
                                                      const int* __restrict__ offsets, const int* __restrict__ deg,
                                                      const float* __restrict__ bgc,
                                                      unsigned short* __restrict__ x1b,
                                                      const int* __restrict__ node_id,
                                                      const float* __restrict__ Wmu, const float* __restrict__ Wvar,
                                                      const float* __restrict__ bmu, const float* __restrict__ bvar,
                                                      float* __restrict__ bcat2, int N) {
    int wave = (blockIdx.x * 256 + threadIdx.x) >> 6;
    int lane = threadIdx.x & 63;
    int n = wave * 4 + (lane >> 4);
    if (n >= N) return;
    gather_core16(xs, srcs, offsets[n], offsets[n + 1], n, lane & 15, deg[n], bgc, x1b,
                  node_id[0], Wmu, Wvar, bmu, bvar, bcat2);
}

__global__ __launch_bounds__(256) void k_gather_csr(const float* __restrict__ xs, const int* __restrict__ srcs,
                                                    const int* __restrict__ offsets, const int* __restrict__ deg,
                                                    const float* __restrict__ bgc,
                                                    unsigned short* __restrict__ x1b,
                                                    const int* __restrict__ node_id,
                                                    const float* __restrict__ Wmu, const float* __restrict__ Wvar,
                                                    const float* __restrict__ bmu, const float* __restrict__ bvar,
                                                    float* __restrict__ bcat2, int N) {
    int wave = (blockIdx.x * 256 + threadIdx.x) >> 6;
    int lane = threadIdx.x & 63;
    int n = wave * 4 + (lane >> 4);
    if (n >= N) return;
    gather_core16(xs, srcs, offsets[n], offsets[n + 1], n, lane & 15, deg[n], bgc, x1b,
                  node_id[0], Wmu, Wvar, bmu, bvar, bcat2);
}

// ---------------- fused per-edge MLP: LDS-free, barrier-free, L2-resident gathers ----------------
// Heads via operand-swapped MFMA: D[dim][edge] = W^T x x2. B-frag gathered straight from the
// 2 MB x1b table (80 B/edge, 16 B/lane). C-layout (col=edge, row=dim) matches noise float4
// loads exactly -> reparam lane-local. Decoder A-frag built with 8 ds_bpermute (no LDS array).
__global__ __launch_bounds__(256) void k_mlp(
    const unsigned short* __restrict__ x1b, const int* __restrict__ rows, const int* __restrict__ cols,
    const float* __restrict__ noise_n, const float* __restrict__ noise_u,
    const unsigned short* __restrict__ Bh2, const unsigned short* __restrict__ Bd1g,
    const float* __restrict__ bcat2, const float* __restrict__ b_d1,
    const float* __restrict__ W_d2, const float* __restrict__ b_d2,
    float* __restrict__ out, int E) {

    int tid = threadIdx.x;
    int e0 = blockIdx.x * BE;
    int l = tid & 63, w = tid >> 6;
    int m = l & 15, g = l >> 4;

    int ea = e0 + w * 16 + m;
    int em = (ea < E) ? ea : E - 1;
    int r = rows[em], c = cols[em];

    // ---- B-frag staging from x1b rows (40 B each; per edge exactly 80 B total) ----
    // kstep0 k=g*8+j: g0: x1r[0-7]; g1: x1r[8-15]; g2: x1r[16-19]+x1c[0-3]; g3: x1c[4-11]
    // kstep1 (g0 only): x1c[12-19]
    const char* br = (const char*)x1b + (size_t)r * 40;
    const char* bc = (const char*)x1b + (size_t)c * 40;
    const char* a0p = (g == 0) ? br : (g == 1) ? br + 16 : (g == 2) ? br + 32 : bc + 8;
    const char* a1p = (g == 0) ? br + 8 : (g == 1) ? br + 24 : (g == 2) ? bc : bc + 16;
    uint2 f0a = *(const uint2*)a0p;
    uint2 f0b = *(const uint2*)a1p;
    union U8 { unsigned u[4]; short8 s; };
    U8 B0u, B1u;
    B0u.u[0] = f0a.x; B0u.u[1] = f0a.y; B0u.u[2] = f0b.x; B0u.u[3] = f0b.y;
    B1u.u[0] = 0u; B1u.u[1] = 0u; B1u.u[2] = 0u; B1u.u[3] = 0u;
    if (g == 0) {
        uint2 f1a = *(const uint2*)(bc + 24);
        uint2 f1b = *(const uint2*)(bc + 32);
        B1u.u[0] = f1a.x; B1u.u[1] = f1a.y; B1u.u[2] = f1b.x; B1u.u[3] = f1b.y;
    }

    // ---- noise + biases in C-layout: lane (g,m) owns dims g*4+r (tile0), 16+g*4+r (tile1,g0) ----
    float4 nz0 = *(const float4*)(noise_n + (size_t)em * H + g * 4);
    float4 bm0 = *(const float4*)(bcat2 + g * 4);
    float4 bv0 = *(const float4*)(bcat2 + 64 + g * 4);
    float4 nz1 = make_float4(0.f, 0.f, 0.f, 0.f), bm1 = nz1, bv1 = nz1;
    if (g == 0) {
        nz1 = *(const float4*)(noise_n + (size_t)em * H + 16);
        bm1 = *(const float4*)(bcat2 + 16);
        bv1 = *(const float4*)(bcat2 + 80);
    }

    // ---- head MFMAs: 4 outputs (mu t0, mu t1, lv t0, lv t1), K-accumulated over 2 ksteps ----
    f32x4 accs[4];
#pragma unroll
    for (int q4 = 0; q4 < 4; q4++) {   // q4 = h*2 + t -> frag f = q4*2 + s
        f32x4 acc = {0.f, 0.f, 0.f, 0.f};
        short8 A0 = *(const short8*)(Bh2 + (q4 * 2 + 0) * 512 + l * 8);
        short8 A1 = *(const short8*)(Bh2 + (q4 * 2 + 1) * 512 + l * 8);
        acc = __builtin_amdgcn_mfma_f32_16x16x32_bf16(A0, B0u.s, acc, 0, 0, 0);
        acc = __builtin_amdgcn_mfma_f32_16x16x32_bf16(A1, B1u.s, acc, 0, 0, 0);
        accs[q4] = acc;
    }

    // ---- reparam, fully lane-local ----
    float nza[4] = {nz0.x, nz0.y, nz0.z, nz0.w};
    float bma[4] = {bm0.x, bm0.y, bm0.z, bm0.w};
    float bva[4] = {bv0.x, bv0.y, bv0.z, bv0.w};
    float nzb[4] = {nz1.x, nz1.y, nz1.z, nz1.w};
    float bmb[4] = {bm1.x, bm1.y, bm1.z, bm1.w};
    float bvb[4] = {bv1.x, bv1.y, bv1.z, bv1.w};
    float z0[4], z1[4];
#pragma unroll
    for (int rr = 0; rr < 4; rr++) {   // tile0 dims g*4+rr (all < 16, valid)
        z0[rr] = accs[0][rr] + bma[rr] + __expf(accs[2][rr] + bva[rr]) * nza[rr];
        z1[rr] = 0.f;                  // tile1 dims 16+g*4+rr: valid only g==0 (16..19)
    }
    if (g == 0) {
#pragma unroll
        for (int rr = 0; rr < 4; rr++)
            z1[rr] = accs[1][rr] + bmb[rr] + __expf(accs[3][rr] + bvb[rr]) * nzb[rr];
    }
    unsigned pz0 = pk2(f2bf(z0[0]), f2bf(z0[1]));
    unsigned pz1 = pk2(f2bf(z0[2]), f2bf(z0[3]));
    unsigned pz2 = pk2(f2bf(z1[0]), f2bf(z1[1]));
    unsigned pz3 = pk2(f2bf(z1[2]), f2bf(z1[3]));

    // ---- transpose to decoder A-layout via ds_bpermute (wave-local, no LDS array) ----
    // target lane (q=g, m) needs z dims q*8..q*8+7 of edge m:
    //   q=0: srcA=(g0,m) srcB=(g1,m) tile0 ; q=1: srcA=(g2,m) srcB=(g3,m) tile0
    //   q=2: srcA=(g0,m) srcB=(g1,m) tile1 (dims 20-23 are g1's zeros) ; q=3: zeros
    int sA = (((2 * g) & 3) * 16 + m) * 4;
    int sB = (((2 * g + 1) & 3) * 16 + m) * 4;
    unsigned qA0 = (unsigned)__builtin_amdgcn_ds_bpermute(sA, (int)pz0);
    unsigned qA1 = (unsigned)__builtin_amdgcn_ds_bpermute(sA, (int)pz1);
    unsigned qB0 = (unsigned)__builtin_amdgcn_ds_bpermute(sB, (int)pz0);
    unsigned qB1 = (unsigned)__builtin_amdgcn_ds_bpermute(sB, (int)pz1);
    unsigned qA2 = (unsigned)__builtin_amdgcn_ds_bpermute(sA, (int)pz2);
    unsigned qA3 = (unsigned)__builtin_amdgcn_ds_bpermute(sA, (int)pz3);
    unsigned qB2 = (unsigned)__builtin_amdgcn_ds_bpermute(sB, (int)pz2);
    unsigned qB3 = (unsigned)__builtin_amdgcn_ds_bpermute(sB, (int)pz3);
    bool hi = (g == 2);
    U8 A2u;
    A2u.u[0] = (g == 3) ? 0u : (hi ? qA2 : qA0);
    A2u.u[1] = (g == 3) ? 0u : (hi ? qA3 : qA1);
    A2u.u[2] = (g == 3) ? 0u : (hi ? qB2 : qB0);
    A2u.u[3] = (g == 3) ? 0u : (hi ? qB3 : qB1);
    short8 a2 = A2u.s;

    // ---- decoder: h = relu(z @ Wd1 + b), sw = relu(h . wd2 + b2), log-free gumbel gate ----
    float p0 = 0.f, p1 = 0.f, p2 = 0.f, p3 = 0.f;
#pragma unroll
    for (int t4 = 0; t4 < 4; t4++) {
        f32x4 acc = {0.f, 0.f, 0.f, 0.f};
        short8 bb = *(const short8*)(Bd1g + t4 * 512 + l * 8);
        acc = __builtin_amdgcn_mfma_f32_16x16x32_bf16(a2, bb, acc, 0, 0, 0);
        int col = t4 * 16 + m;
        float bias = b_d1[col], wo = W_d2[col];
        p0 += fmaxf(acc[0] + bias, 0.f) * wo;
        p1 += fmaxf(acc[1] + bias, 0.f) * wo;
        p2 += fmaxf(acc[2] + bias, 0.f) * wo;
        p3 += fmaxf(acc[3] + bias, 0.f) * wo;
    }
    p0 = sum16(p0); p1 = sum16(p1); p2 = sum16(p2); p3 = sum16(p3);
    if (m < 4) {
        float swv = (m == 0) ? p0 : (m == 1) ? p1 : (m == 2) ? p2 : p3;
        int e = e0 + w * 16 + g * 4 + m;
        if (e < E) {
            float sw = fmaxf(swv + b_d2[0], 0.f);
            float u = noise_u[e];
            float ev = 0.9999f - 0.9998f * u;
            // sigmoid(log(ev/(1-ev)) + sw) == ev / (ev + (1-ev)*exp(-sw))
            float t = __expf(-sw);
            out[e] = ev / (ev + (1.f - ev) * t);
        }
    }
}

extern "C" void kernel_launch(void* const* d_in, const int* in_sizes, int n_in,
                              void* d_out, int out_size, void* d_ws, size_t ws_size,
                              hipStream_t stream) {
    const int N = in_sizes[0] / NFEAT;   // 50000
    const int E = in_sizes[1] / 2;       // 1600000

    const float* x       = (const float*)d_in[0];
    const int*   ei      = (const int*)d_in[1];
    const int*   rows    = ei;
    const int*   cols    = ei + E;
    const int*   node_id = (const int*)d_in[2];
    const float* noise_n = (const float*)d_in[3];
    const float* noise_u = (const float*)d_in[4];
    const float* Wgc  = (const float*)d_in[5];
    const float* bgc  = (const float*)d_in[6];
    const float* Wmu  = (const float*)d_in[7];
    const float* bmu  = (const float*)d_in[8];
    const float* Wvar = (const float*)d_in[9];
    const float* bvar = (const float*)d_in[10];
    const float* Wd1  = (const float*)d_in[11];
    const float* bd1  = (const float*)d_in[12];
    const float* Wd2  = (const float*)d_in[13];
    const float* bd2  = (const float*)d_in[14];
    float* out = (float*)d_out;

    const int B = 256;
    int gN  = (N + B - 1) / B;
    int gG  = (N + 15) / 16;            // gather: 16 nodes per block (4 waves x 4 nodes)
    int gE  = (E + B - 1) / B;
    int gM  = (E + BE - 1) / BE;
    int nBins = (N + 255) / 256;        // <= 256 for N <= 65536
    int chunk = (E + NB - 1) / NB;

    char* ws = (char*)d_ws;
    size_t wstride   = (size_t)((N + 3) >> 2);
    // main-path layout (256B-aligned regions)
    size_t o_deg     = 0;
    size_t o_off     = o_deg  + (((size_t)N * 4 + 255) & ~255ULL);
    size_t o_csum    = o_off  + (((size_t)(N + 1) * 4 + 255) & ~255ULL);
    size_t o_coff    = o_csum + 1024;
    size_t o_hist    = o_coff + 1024;
    size_t o_delta   = o_hist  + ((NB * wstride * 4 + 255) & ~255ULL);
    size_t o_rank    = o_delta + (((size_t)NB * N + 255) & ~255ULL);
    size_t o_srcs    = o_rank  + (((size_t)E + 255) & ~255ULL);
    size_t o_xs      = o_srcs  + (((size_t)E * 2 + 255) & ~255ULL);
    size_t o_x1b     = o_xs    + (((size_t)N * H * 4 + 255) & ~255ULL);
    size_t o_Bh2     = o_x1b   + (((size_t)N * H * 2 + 255) & ~255ULL);
    size_t o_Bd1     = o_Bh2   + 8192;
    size_t o_bcat2   = o_Bd1   + 4096;
    size_t need      = o_bcat2 + 512;

    bool main_path = (ws_size >= need) && (N <= 4 * HW) && (N < 65536) && (nBins <= 256);

    if (main_path) {
        int*   deg     = (int*)(ws + o_deg);
        int*   offsets = (int*)(ws + o_off);
        int*   csum    = (int*)(ws + o_csum);
        int*   coff    = (int*)(ws + o_coff);
        unsigned* hist = (unsigned*)(ws + o_hist);
        unsigned char* delta = (unsigned char*)(ws + o_delta);
        unsigned char* rank  = (unsigned char*)(ws + o_rank);
        unsigned short* srcs = (unsigned short*)(ws + o_srcs);
        float* xs      = (float*)(ws + o_xs);
        unsigned short* x1b  = (unsigned short*)(ws + o_x1b);
        unsigned short* Bh2  = (unsigned short*)(ws + o_Bh2);
        unsigned short* Bd1  = (unsigned short*)(ws + o_Bd1);
        float* bcat2   = (float*)(ws + o_bcat2);

        k_prep<<<gN, B, 0, stream>>>(Wmu, Wvar, Wd1, Bh2, Bd1, deg, csum, bcat2, N);
        k_hist<<<NB, 512, 0, stream>>>(cols, hist, csum, rank, E, N);
        k_scansmall<<<1, B, 0, stream>>>(csum, coff, nBins);
        k_bases<<<nBins, B, 0, stream>>>(hist, coff, delta, offsets, deg, N, E);
        k_xw_xs<<<gN, B, 0, stream>>>(x, Wgc, deg, xs, N);
        k_place<<<gE, B, 0, stream>>>(rows, cols, offsets, delta, rank, srcs, E, N, chunk);
        k_gather_csr16<<<gG, B, 0, stream>>>(xs, srcs, offsets, deg, bgc, x1b,
                                             node_id, Wmu, Wvar, bmu, bvar, bcat2, N);
        k_mlp<<<gM, B, 0, stream>>>(x1b, rows, cols, noise_n, noise_u,
                                    Bh2, Bd1, bcat2, bd1, Wd2, bd2, out, E);
    } else {
        size_t f_deg   = 0;
        size_t f_off   = f_deg + (((size_t)N * 4 + 255) & ~255ULL);
        size_t f_cur   = f_off + (((size_t)(N + 1) * 4 + 255) & ~255ULL);
        size_t f_srcs  = f_cur + (((size_t)N * 4 + 255) & ~255ULL);
        size_t f_xs    = f_srcs + (((size_t)E * 4 + 255) & ~255ULL);
        size_t f_x1b   = f_xs + (((size_t)N * H * 4 + 255) & ~255ULL);
        size_t f_Bh2   = f_x1b + (((size_t)N * H * 2 + 255) & ~255ULL);
        size_t f_Bd1   = f_Bh2 + 8192;
        size_t f_bcat2 = f_Bd1 + 4096;

        int*   deg     = (int*)(ws + f_deg);
        int*   offsets = (int*)(ws + f_off);
        int*   cursor  = (int*)(ws + f_cur);
        int*   srcs    = (int*)(ws + f_srcs);
        float* xs      = (float*)(ws + f_xs);
        unsigned short* x1b = (unsigned short*)(ws + f_x1b);
        unsigned short* Bh2 = (unsigned short*)(ws + f_Bh2);
        unsigned short* Bd1 = (unsigned short*)(ws + f_Bd1);
        float* bcat2   = (float*)(ws + f_bcat2);

        k_prep<<<gN, B, 0, stream>>>(Wmu, Wvar, Wd1, Bh2, Bd1, deg, cursor, bcat2, N);
        k_deg<<<gE, B, 0, stream>>>(cols, deg, E);
        k_scan<<<1, SCAN_T, 0, stream>>>(deg, offsets, cursor, N);
        k_bucket_csr<<<gE, B, 0, stream>>>(rows, cols, cursor, srcs, E);
        k_xw_xs<<<gN, B, 0, stream>>>(x, Wgc, deg, xs, N);
        k_gather_csr<<<gG, B, 0, stream>>>(xs, srcs, offsets, deg, bgc, x1b,
                                           node_id, Wmu, Wvar, bmu, bvar, bcat2, N);
        k_mlp<<<gM, B, 0, stream>>>(x1b, rows, cols, noise_n, noise_u,
                                    Bh2, Bd1, bcat2, bd1, Wd2, bd2, out, E);
    }
}